// Round 10
// baseline (187.752 us; speedup 1.0000x reference)
//
#include <hip/hip_runtime.h>
#include <hip/hip_bf16.h>

#if defined(__has_builtin)
#if __has_builtin(__builtin_amdgcn_mfma_f32_16x16x16bf16_1k)
#define HAVE_MFMA16 1
#endif
#endif
#ifndef HAVE_MFMA16
#define HAVE_MFMA16 0
#endif

namespace {

constexpr int B = 2, S = 2048, E = 512, H = 8, D = 64, HD = 512;
constexpr float SL = 0.125f * 1.44269504f;  // (1/sqrt(64)) * log2(e)

typedef __attribute__((ext_vector_type(8))) short bf16x8;
typedef __attribute__((ext_vector_type(4))) short bf16x4;
typedef __attribute__((ext_vector_type(4))) unsigned short u16x4;
typedef __attribute__((ext_vector_type(4))) float f32x4;
typedef __attribute__((ext_vector_type(4))) float float4v;

__device__ __forceinline__ ushort f2b(float x) {
  __hip_bfloat16 h = __float2bfloat16(x);
  return *reinterpret_cast<const ushort*>(&h);
}

// ---------------------------------------------------------------------------
// Fused prep. blocks [0,512): K/V convert+transpose; [512,640): W transpose;
// [640,8832): mask -> ballot keep bits (4096 rows x 8 chunks = 32768 waves).
// keep layout: uint4 per (row, 128k-tile); component r bit i = keep(k=tile*128+4i+r).
__global__ __launch_bounds__(256) void prep_fused_kernel(
    const float* __restrict__ K, const float* __restrict__ V,
    const float* __restrict__ Wq, const float* __restrict__ Wo,
    const int* __restrict__ maskp,
    ushort* __restrict__ Kbf, ushort* __restrict__ Vtbf,
    ushort* __restrict__ Wtq, ushort* __restrict__ Wto,
    uint4* __restrict__ keep4) {
  const int bid = blockIdx.x;
  const int t = threadIdx.x;
  if (bid < 512) {
    __shared__ __align__(16) ushort Vn[64][76];
    const int kt = bid & 31;
    const int bh = bid >> 5;
    const int b = bh >> 3, h = bh & 7;
    const int k0 = kt * 64;
#pragma unroll
    for (int i = 0; i < 4; ++i) {
      int c = i * 256 + t;
      int kk = c >> 4, d4 = (c & 15) * 4;
      size_t g = ((size_t)(b * 2048 + k0 + kk) * 8 + h) * 64 + d4;
      float4v kv = *(const float4v*)(K + g);
      float4v vv = *(const float4v*)(V + g);
      u16x4 kp = {f2b(kv.x), f2b(kv.y), f2b(kv.z), f2b(kv.w)};
      u16x4 vp = {f2b(vv.x), f2b(vv.y), f2b(vv.z), f2b(vv.w)};
      *(u16x4*)(Kbf + ((size_t)(bh * 2048 + k0 + kk)) * 64 + d4) = kp;
      *(u16x4*)&Vn[kk][d4] = vp;
    }
    __syncthreads();
#pragma unroll
    for (int i = 0; i < 2; ++i) {
      int c = i * 256 + t;
      int kc8 = (c & 7) * 8, d = c >> 3;
      union { ushort u[8]; bf16x8 v; } p;
#pragma unroll
      for (int j = 0; j < 8; ++j) p.u[j] = Vn[kc8 + j][d];
      *(bf16x8*)(Vtbf + ((size_t)(bh * 64 + d)) * 2048 + k0 + kc8) = p.v;
    }
  } else if (bid < 640) {
    __shared__ __align__(16) ushort T[64][68];
    const int idx = bid - 512;
    const float* Wsrc = (idx >> 6) ? Wo : Wq;
    ushort* Wdst = (idx >> 6) ? Wto : Wtq;
    const int x = idx & 63;
    const int k0 = (x & 7) * 64, n0 = (x >> 3) * 64;
#pragma unroll
    for (int i = 0; i < 4; ++i) {
      int c = i * 256 + t;
      int kk = c >> 4, n4 = (c & 15) * 4;
      float4v v = *(const float4v*)(Wsrc + (size_t)(k0 + kk) * 512 + n0 + n4);
      u16x4 p = {f2b(v.x), f2b(v.y), f2b(v.z), f2b(v.w)};
      *(u16x4*)&T[kk][n4] = p;
    }
    __syncthreads();
#pragma unroll
    for (int i = 0; i < 2; ++i) {
      int c = i * 256 + t;
      int n = c >> 3, k8 = (c & 7) * 8;
      union { ushort u[8]; bf16x8 v; } p;
#pragma unroll
      for (int j = 0; j < 8; ++j) p.u[j] = T[k8 + j][n];
      *(bf16x8*)(Wdst + (size_t)(n0 + n) * 512 + k0 + k8) = p.v;
    }
  } else {
    // mask: wave per 256-k chunk of one row; 4096 rows x 8 chunks
    const int wid = (bid - 640) * 4 + (t >> 6);  // 0..32767
    const int row = wid >> 3, c = wid & 7;
    const int lane = t & 63;
    const int4 v = *((const int4*)(maskp + (size_t)row * 2048 + c * 256) + lane);
    unsigned long long bx = __ballot(v.x == 0);
    unsigned long long by = __ballot(v.y == 0);
    unsigned long long bz = __ballot(v.z == 0);
    unsigned long long bw = __ballot(v.w == 0);
    if (lane == 0)
      keep4[(size_t)row * 16 + c * 2] = uint4{(uint)bx, (uint)by, (uint)bz, (uint)bw};
    if (lane == 32)
      keep4[(size_t)row * 16 + c * 2 + 1] =
          uint4{(uint)(bx >> 32), (uint)(by >> 32), (uint)(bz >> 32), (uint)(bw >> 32)};
  }
}

// ---------------------------------------------------------------------------
// proj_q: Qbf[b][h][q][d] (bf16) = inputs(fp32) @ Wq. LDS-free: wave = 32x32 tile,
// MFMA fragments loaded directly from global (Wt is [n][k] bf16).
__global__ __launch_bounds__(256) void proj_q_kernel(
    const float* __restrict__ A, const ushort* __restrict__ Wt, ushort* __restrict__ Qbf) {
  const int tid = threadIdx.x, lane = tid & 63, w = tid >> 6;
  const int col = lane & 15, quad = lane >> 4, quad4 = quad * 4;
  const int wid = blockIdx.x * 4 + w;       // 2048 wave-tiles
  const int m0 = (wid >> 4) * 32, n0 = (wid & 15) * 32;

  f32x4 acc[2][2];
#pragma unroll
  for (int i = 0; i < 2; ++i)
#pragma unroll
    for (int j = 0; j < 2; ++j) acc[i][j] = f32x4{0.f, 0.f, 0.f, 0.f};

  const float* Ap0 = A + (size_t)(m0 + col) * 512 + quad * 8;
  const float* Ap1 = Ap0 + (size_t)16 * 512;
  const ushort* Wp0 = Wt + (size_t)(n0 + col) * 512 + quad * 8;
  const ushort* Wp1 = Wp0 + (size_t)16 * 512;

#pragma unroll 4
  for (int kt = 0; kt < 16; ++kt) {
    const int k0 = kt * 32;
    float4v a0a = *(const float4v*)(Ap0 + k0);
    float4v a0b = *(const float4v*)(Ap0 + k0 + 4);
    float4v a1a = *(const float4v*)(Ap1 + k0);
    float4v a1b = *(const float4v*)(Ap1 + k0 + 4);
    bf16x8 wb0 = *(const bf16x8*)(Wp0 + k0);
    bf16x8 wb1 = *(const bf16x8*)(Wp1 + k0);
    union { ushort u[8]; bf16x8 v; } ah0, ah1;
    ah0.u[0] = f2b(a0a.x); ah0.u[1] = f2b(a0a.y); ah0.u[2] = f2b(a0a.z); ah0.u[3] = f2b(a0a.w);
    ah0.u[4] = f2b(a0b.x); ah0.u[5] = f2b(a0b.y); ah0.u[6] = f2b(a0b.z); ah0.u[7] = f2b(a0b.w);
    ah1.u[0] = f2b(a1a.x); ah1.u[1] = f2b(a1a.y); ah1.u[2] = f2b(a1a.z); ah1.u[3] = f2b(a1a.w);
    ah1.u[4] = f2b(a1b.x); ah1.u[5] = f2b(a1b.y); ah1.u[6] = f2b(a1b.z); ah1.u[7] = f2b(a1b.w);
    acc[0][0] = __builtin_amdgcn_mfma_f32_16x16x32_bf16(ah0.v, wb0, acc[0][0], 0, 0, 0);
    acc[0][1] = __builtin_amdgcn_mfma_f32_16x16x32_bf16(ah0.v, wb1, acc[0][1], 0, 0, 0);
    acc[1][0] = __builtin_amdgcn_mfma_f32_16x16x32_bf16(ah1.v, wb0, acc[1][0], 0, 0, 0);
    acc[1][1] = __builtin_amdgcn_mfma_f32_16x16x32_bf16(ah1.v, wb1, acc[1][1], 0, 0, 0);
  }

#pragma unroll
  for (int i = 0; i < 2; ++i)
#pragma unroll
    for (int j = 0; j < 2; ++j)
#pragma unroll
      for (int r = 0; r < 4; ++r) {
        int m = m0 + i * 16 + quad4 + r;
        int n = n0 + j * 16 + col;
        int b = m >> 11, q = m & 2047, h = n >> 6, dd = n & 63;
        Qbf[((size_t)(b * 8 + h) * 2048 + q) * 64 + dd] = f2b(acc[i][j][r]);
      }
}

// ---------------------------------------------------------------------------
// proj_out: out fp32 = attnb(bf16) @ Wo. LDS-free streaming.
__global__ __launch_bounds__(256) void proj_out_kernel(
    const ushort* __restrict__ A, const ushort* __restrict__ Wt, float* __restrict__ C) {
  const int tid = threadIdx.x, lane = tid & 63, w = tid >> 6;
  const int col = lane & 15, quad = lane >> 4, quad4 = quad * 4;
  const int wid = blockIdx.x * 4 + w;
  const int m0 = (wid >> 4) * 32, n0 = (wid & 15) * 32;

  f32x4 acc[2][2];
#pragma unroll
  for (int i = 0; i < 2; ++i)
#pragma unroll
    for (int j = 0; j < 2; ++j) acc[i][j] = f32x4{0.f, 0.f, 0.f, 0.f};

  const ushort* Ap0 = A + (size_t)(m0 + col) * 512 + quad * 8;
  const ushort* Ap1 = Ap0 + (size_t)16 * 512;
  const ushort* Wp0 = Wt + (size_t)(n0 + col) * 512 + quad * 8;
  const ushort* Wp1 = Wp0 + (size_t)16 * 512;

#pragma unroll 4
  for (int kt = 0; kt < 16; ++kt) {
    const int k0 = kt * 32;
    bf16x8 ah0 = *(const bf16x8*)(Ap0 + k0);
    bf16x8 ah1 = *(const bf16x8*)(Ap1 + k0);
    bf16x8 wb0 = *(const bf16x8*)(Wp0 + k0);
    bf16x8 wb1 = *(const bf16x8*)(Wp1 + k0);
    acc[0][0] = __builtin_amdgcn_mfma_f32_16x16x32_bf16(ah0, wb0, acc[0][0], 0, 0, 0);
    acc[0][1] = __builtin_amdgcn_mfma_f32_16x16x32_bf16(ah0, wb1, acc[0][1], 0, 0, 0);
    acc[1][0] = __builtin_amdgcn_mfma_f32_16x16x32_bf16(ah1, wb0, acc[1][0], 0, 0, 0);
    acc[1][1] = __builtin_amdgcn_mfma_f32_16x16x32_bf16(ah1, wb1, acc[1][1], 0, 0, 0);
  }

#pragma unroll
  for (int i = 0; i < 2; ++i)
#pragma unroll
    for (int j = 0; j < 2; ++j)
#pragma unroll
      for (int r = 0; r < 4; ++r)
        C[(size_t)(m0 + i * 16 + quad4 + r) * 512 + n0 + j * 16 + col] = acc[i][j][r];
}

// ---------------------------------------------------------------------------
// Flash attention: S^T orientation, static-max softmax, PV from registers via
// 16x16x16 MFMA (A-frag k=quad*4+j == S^T C-layout row k=quad*4+r).
__global__ __launch_bounds__(256) void flash_attn_kernel(
    const ushort* __restrict__ Qbf, const ushort* __restrict__ Kbf,
    const ushort* __restrict__ Vtbf, const uint4* __restrict__ keep4,
    ushort* __restrict__ Op) {
  __shared__ __align__(16) ushort Ks[128][72];
  __shared__ __align__(16) ushort Vt[64][136];
#if !HAVE_MFMA16
  __shared__ __align__(16) ushort PQ[64][136];
#endif

  const int bid = blockIdx.x;
  const int qt = bid & 31;
  const int bh = bid >> 5;
  const int b = bh >> 3, h = bh & 7;
  const int q0 = qt * 64;
  const int tid = threadIdx.x, lane = tid & 63, w = tid >> 6;
  const int col = lane & 15, quad = lane >> 4, quad4 = quad * 4;

  // stage Q (64x64 bf16) into Ks rows 0..63, grab B-frags, then release Ks
  const ushort* Qt = Qbf + (size_t)(bh * 2048 + q0) * 64;
#pragma unroll
  for (int i = 0; i < 2; ++i) {
    int c = i * 256 + tid;
    *(bf16x8*)&Ks[c >> 3][(c & 7) * 8] = *(const bf16x8*)(Qt + c * 8);
  }
  __syncthreads();
  const bf16x8 qb0 = *(const bf16x8*)&Ks[w * 16 + col][quad * 8];
  const bf16x8 qb1 = *(const bf16x8*)&Ks[w * 16 + col][32 + quad * 8];
  __syncthreads();  // Q fragment reads complete before tile-0 staging

  f32x4 oacc[4];
#pragma unroll
  for (int c = 0; c < 4; ++c) oacc[c] = f32x4{0.f, 0.f, 0.f, 0.f};
  float l = 0.f;

  const uint4* kr = keep4 + (size_t)(b * 2048 + q0 + w * 16 + col) * 16;
  const ushort* Kbase = Kbf + (size_t)bh * 2048 * 64;
  const ushort* Vbase = Vtbf + (size_t)bh * 64 * 2048;

  bf16x8 kpre[4], vpre[4];
  uint4 kw = kr[0];
#pragma unroll
  for (int i = 0; i < 4; ++i) {
    int c = i * 256 + tid;
    kpre[i] = *(const bf16x8*)(Kbase + (size_t)c * 8);
    int d = c >> 4, k8 = (c & 15) * 8;
    vpre[i] = *(const bf16x8*)(Vbase + (size_t)d * 2048 + k8);
  }

  for (int kt = 0; kt < 16; ++kt) {
    if (kt) __syncthreads();
#pragma unroll
    for (int i = 0; i < 4; ++i) {
      int c = i * 256 + tid;
      *(bf16x8*)&Ks[c >> 3][(c & 7) * 8] = kpre[i];
      int d = c >> 4, k8 = (c & 15) * 8;
      *(bf16x8*)&Vt[d][k8] = vpre[i];
    }
    uint4 kwn = kw;
    if (kt < 15) {
      const int k1 = (kt + 1) * 128;
      kwn = kr[kt + 1];
#pragma unroll
      for (int i = 0; i < 4; ++i) {
        int c = i * 256 + tid;
        kpre[i] = *(const bf16x8*)(Kbase + (size_t)k1 * 64 + c * 8);
        int d = c >> 4, k8 = (c & 15) * 8;
        vpre[i] = *(const bf16x8*)(Vbase + (size_t)d * 2048 + k1 + k8);
      }
    }
    __syncthreads();

    // S^T: 128 k-rows x 16 q-cols per wave
    f32x4 sc[8];
#pragma unroll
    for (int t = 0; t < 8; ++t) sc[t] = f32x4{0.f, 0.f, 0.f, 0.f};
#pragma unroll
    for (int t = 0; t < 8; ++t) {
      bf16x8 ka0 = *(const bf16x8*)&Ks[t * 16 + col][quad * 8];
      bf16x8 ka1 = *(const bf16x8*)&Ks[t * 16 + col][32 + quad * 8];
      sc[t] = __builtin_amdgcn_mfma_f32_16x16x32_bf16(ka0, qb0, sc[t], 0, 0, 0);
      sc[t] = __builtin_amdgcn_mfma_f32_16x16x32_bf16(ka1, qb1, sc[t], 0, 0, 0);
    }

    // static-max softmax: p = 2^(s*SL) * keep  (|s*SL| <= ~10, no overflow)
    const uint mx_ = kw.x >> quad, my_ = kw.y >> quad, mz_ = kw.z >> quad, mw_ = kw.w >> quad;
    float rs = 0.f;
#pragma unroll
    for (int t = 0; t < 8; ++t) {
      const int sh = 4 * t;
      float p0 = ((mx_ >> sh) & 1u) ? exp2f(sc[t][0] * SL) : 0.f;
      float p1 = ((my_ >> sh) & 1u) ? exp2f(sc[t][1] * SL) : 0.f;
      float p2 = ((mz_ >> sh) & 1u) ? exp2f(sc[t][2] * SL) : 0.f;
      float p3 = ((mw_ >> sh) & 1u) ? exp2f(sc[t][3] * SL) : 0.f;
      sc[t][0] = p0; sc[t][1] = p1; sc[t][2] = p2; sc[t][3] = p3;
      rs += (p0 + p1) + (p2 + p3);
    }
    rs += __shfl_xor(rs, 16);
    rs += __shfl_xor(rs, 32);
    l += rs;

#if HAVE_MFMA16
    // PV: P directly from registers, 16x16x16 MFMA
#pragma unroll
    for (int t = 0; t < 8; ++t) {
      union { ushort u[4]; bf16x4 v; } pa;
      pa.u[0] = f2b(sc[t][0]); pa.u[1] = f2b(sc[t][1]);
      pa.u[2] = f2b(sc[t][2]); pa.u[3] = f2b(sc[t][3]);
#pragma unroll
      for (int c = 0; c < 4; ++c) {
        bf16x4 vb = *(const bf16x4*)&Vt[c * 16 + col][t * 16 + quad4];
        oacc[c] = __builtin_amdgcn_mfma_f32_16x16x16bf16_1k(pa.v, vb, oacc[c], 0, 0, 0);
      }
    }
#else
    // fallback: LDS round-trip + 16x16x32
#pragma unroll
    for (int t = 0; t < 8; ++t) {
      u16x4 pk = {f2b(sc[t][0]), f2b(sc[t][1]), f2b(sc[t][2]), f2b(sc[t][3])};
      *(u16x4*)&PQ[w * 16 + col][t * 16 + quad4] = pk;
    }
    __threadfence_block();
    bf16x8 pa[4];
#pragma unroll
    for (int kb = 0; kb < 4; ++kb)
      pa[kb] = *(const bf16x8*)&PQ[w * 16 + col][kb * 32 + quad * 8];
#pragma unroll
    for (int c = 0; c < 4; ++c)
#pragma unroll
      for (int kb = 0; kb < 4; ++kb) {
        bf16x8 vb = *(const bf16x8*)&Vt[c * 16 + col][kb * 32 + quad * 8];
        oacc[c] = __builtin_amdgcn_mfma_f32_16x16x32_bf16(pa[kb], vb, oacc[c], 0, 0, 0);
      }
#endif
    kw = kwn;
  }

  const float inv = 1.f / l;
  float invO[4];
#pragma unroll
  for (int r = 0; r < 4; ++r) invO[r] = __shfl(inv, quad4 + r);
#pragma unroll
  for (int c = 0; c < 4; ++c)
#pragma unroll
    for (int r = 0; r < 4; ++r)
      Op[(size_t)(b * S + q0 + w * 16 + quad4 + r) * HD + h * D + c * 16 + col] =
          f2b(oacc[c][r] * invO[r]);
}

}  // namespace

extern "C" void kernel_launch(void* const* d_in, const int* in_sizes, int n_in,
                              void* d_out, int out_size, void* d_ws, size_t ws_size,
                              hipStream_t stream) {
  const float* inputs = (const float*)d_in[0];   // (B,S,E)
  const float* keys   = (const float*)d_in[1];   // (B,S,H,D)
  const float* values = (const float*)d_in[2];   // (B,S,H,D)
  const float* wq     = (const float*)d_in[3];   // (E, HD)
  const float* wo     = (const float*)d_in[4];   // (HD, E)
  const int*   maskp  = (const int*)d_in[5];     // (B,S,S) bool as int32
  float* out = (float*)d_out;                    // (B,S,E)

  // d_out (8 MB) doubles as scratch for K/V bf16 until proj_out overwrites it.
  ushort* Kbf  = (ushort*)d_out;                 // (B,H,S,D) bf16, 4 MB
  ushort* Vtbf = Kbf + (size_t)2097152;          // (B,H,D,S) bf16, 4 MB

  char* ws = (char*)d_ws;
  ushort* Qbf   = (ushort*)ws;                   // 4 MB
  ushort* attnb = (ushort*)(ws + (4 << 20));     // 4 MB
  uint4*  keep4 = (uint4*)(ws + (8 << 20));      // 1 MB
  ushort* Wtq   = (ushort*)(ws + (9 << 20));     // 0.5 MB
  ushort* Wto   = (ushort*)(ws + (9 << 20) + (512 << 10));  // 0.5 MB

  dim3 blk(256);
  prep_fused_kernel<<<dim3(8832), blk, 0, stream>>>(keys, values, wq, wo, maskp,
                                                    Kbf, Vtbf, Wtq, Wto, keep4);
  proj_q_kernel<<<dim3(512), blk, 0, stream>>>(inputs, Wtq, Qbf);
  flash_attn_kernel<<<dim3(512), blk, 0, stream>>>(Qbf, Kbf, Vtbf, keep4, attnb);
  proj_out_kernel<<<dim3(512), blk, 0, stream>>>(attnb, Wto, out);
}

// Round 11
// 168.535 us; speedup vs baseline: 1.1140x; 1.1140x over previous
//
#include <hip/hip_runtime.h>
#include <hip/hip_bf16.h>

namespace {

constexpr int B = 2, S = 2048, E = 512, H = 8, D = 64, HD = 512;
constexpr float SL = 0.125f * 1.44269504f;  // (1/sqrt(64)) * log2(e)
constexpr int PLD = 40;                     // proj LDS row stride (bf16)

typedef __attribute__((ext_vector_type(8))) short bf16x8;
typedef __attribute__((ext_vector_type(4))) unsigned short u16x4;
typedef __attribute__((ext_vector_type(4))) float f32x4;
typedef __attribute__((ext_vector_type(4))) float float4v;

__device__ __forceinline__ ushort f2b(float x) {
  __hip_bfloat16 h = __float2bfloat16(x);
  return *reinterpret_cast<const ushort*>(&h);
}

// ---------------------------------------------------------------------------
// Fused prep. blocks [0,512): K/V convert+transpose; [512,640): W transpose;
// [640,8832): mask -> ballot keep bits (4096 rows x 8 chunks = 32768 waves).
// keep layout: uint4 per (row, 128k-tile); component r bit i = keep(k=tile*128+4i+r).
__global__ __launch_bounds__(256) void prep_fused_kernel(
    const float* __restrict__ K, const float* __restrict__ V,
    const float* __restrict__ Wq, const float* __restrict__ Wo,
    const int* __restrict__ maskp,
    ushort* __restrict__ Kbf, ushort* __restrict__ Vtbf,
    ushort* __restrict__ Wtq, ushort* __restrict__ Wto,
    uint4* __restrict__ keep4) {
  const int bid = blockIdx.x;
  const int t = threadIdx.x;
  if (bid < 512) {
    __shared__ __align__(16) ushort Vn[64][76];
    const int kt = bid & 31;
    const int bh = bid >> 5;
    const int b = bh >> 3, h = bh & 7;
    const int k0 = kt * 64;
#pragma unroll
    for (int i = 0; i < 4; ++i) {
      int c = i * 256 + t;
      int kk = c >> 4, d4 = (c & 15) * 4;
      size_t g = ((size_t)(b * 2048 + k0 + kk) * 8 + h) * 64 + d4;
      float4v kv = *(const float4v*)(K + g);
      float4v vv = *(const float4v*)(V + g);
      u16x4 kp = {f2b(kv.x), f2b(kv.y), f2b(kv.z), f2b(kv.w)};
      u16x4 vp = {f2b(vv.x), f2b(vv.y), f2b(vv.z), f2b(vv.w)};
      *(u16x4*)(Kbf + ((size_t)(bh * 2048 + k0 + kk)) * 64 + d4) = kp;
      *(u16x4*)&Vn[kk][d4] = vp;
    }
    __syncthreads();
#pragma unroll
    for (int i = 0; i < 2; ++i) {
      int c = i * 256 + t;
      int kc8 = (c & 7) * 8, d = c >> 3;
      union { ushort u[8]; bf16x8 v; } p;
#pragma unroll
      for (int j = 0; j < 8; ++j) p.u[j] = Vn[kc8 + j][d];
      *(bf16x8*)(Vtbf + ((size_t)(bh * 64 + d)) * 2048 + k0 + kc8) = p.v;
    }
  } else if (bid < 640) {
    __shared__ __align__(16) ushort T[64][68];
    const int idx = bid - 512;
    const float* Wsrc = (idx >> 6) ? Wo : Wq;
    ushort* Wdst = (idx >> 6) ? Wto : Wtq;
    const int x = idx & 63;
    const int k0 = (x & 7) * 64, n0 = (x >> 3) * 64;
#pragma unroll
    for (int i = 0; i < 4; ++i) {
      int c = i * 256 + t;
      int kk = c >> 4, n4 = (c & 15) * 4;
      float4v v = *(const float4v*)(Wsrc + (size_t)(k0 + kk) * 512 + n0 + n4);
      u16x4 p = {f2b(v.x), f2b(v.y), f2b(v.z), f2b(v.w)};
      *(u16x4*)&T[kk][n4] = p;
    }
    __syncthreads();
#pragma unroll
    for (int i = 0; i < 2; ++i) {
      int c = i * 256 + t;
      int n = c >> 3, k8 = (c & 7) * 8;
      union { ushort u[8]; bf16x8 v; } p;
#pragma unroll
      for (int j = 0; j < 8; ++j) p.u[j] = T[k8 + j][n];
      *(bf16x8*)(Wdst + (size_t)(n0 + n) * 512 + k0 + k8) = p.v;
    }
  } else {
    // mask: wave per 256-k chunk of one row; 4096 rows x 8 chunks
    const int wid = (bid - 640) * 4 + (t >> 6);  // 0..32767
    const int row = wid >> 3, c = wid & 7;
    const int lane = t & 63;
    const int4 v = *((const int4*)(maskp + (size_t)row * 2048 + c * 256) + lane);
    unsigned long long bx = __ballot(v.x == 0);
    unsigned long long by = __ballot(v.y == 0);
    unsigned long long bz = __ballot(v.z == 0);
    unsigned long long bw = __ballot(v.w == 0);
    if (lane == 0)
      keep4[(size_t)row * 16 + c * 2] = uint4{(uint)bx, (uint)by, (uint)bz, (uint)bw};
    if (lane == 32)
      keep4[(size_t)row * 16 + c * 2 + 1] =
          uint4{(uint)(bx >> 32), (uint)(by >> 32), (uint)(bz >> 32), (uint)(bw >> 32)};
  }
}

// ---------------------------------------------------------------------------
// proj_q: Qbf[b][h][q][d] (bf16) = inputs @ Wq, plain bf16 A, pipelined LDS staging.
__global__ __launch_bounds__(256) void proj_q_kernel(
    const float* __restrict__ A, const ushort* __restrict__ Wt, ushort* __restrict__ Qbf) {
  __shared__ __align__(16) ushort As[64][PLD];
  __shared__ __align__(16) ushort Ws[64][PLD];

  const int tid = threadIdx.x;
  const int lane = tid & 63;
  const int w = tid >> 6;
  const int col = lane & 15;
  const int quad = lane >> 4;
  const int m0 = blockIdx.y * 64;
  const int n0 = blockIdx.x * 64;
  const int wm = (w & 1) * 32;
  const int wn = (w >> 1) * 32;
  const int ar = tid >> 2;
  const int ak = (tid & 3) * 8;
  const int wn2 = tid >> 2;
  const int wkc = (tid & 3) * 8;

  f32x4 acc[2][2];
#pragma unroll
  for (int i = 0; i < 2; ++i)
#pragma unroll
    for (int j = 0; j < 2; ++j) acc[i][j] = f32x4{0.f, 0.f, 0.f, 0.f};

  const float* Ap = A + (size_t)(m0 + ar) * 512 + ak;
  const ushort* Wp = Wt + (size_t)(n0 + wn2) * 512 + wkc;
  float4v a0p = *(const float4v*)Ap;
  float4v a1p = *(const float4v*)(Ap + 4);
  bf16x8 wp = *(const bf16x8*)Wp;

  for (int kt = 0; kt < 16; ++kt) {
    if (kt) __syncthreads();
    {
      union { ushort u[8]; bf16x8 v; } ap;
      ap.u[0] = f2b(a0p.x); ap.u[1] = f2b(a0p.y); ap.u[2] = f2b(a0p.z); ap.u[3] = f2b(a0p.w);
      ap.u[4] = f2b(a1p.x); ap.u[5] = f2b(a1p.y); ap.u[6] = f2b(a1p.z); ap.u[7] = f2b(a1p.w);
      *(bf16x8*)&As[ar][ak] = ap.v;
      *(bf16x8*)&Ws[wn2][wkc] = wp;
    }
    if (kt < 15) {
      const int k1 = (kt + 1) * 32;
      a0p = *(const float4v*)(Ap + k1);
      a1p = *(const float4v*)(Ap + k1 + 4);
      wp = *(const bf16x8*)(Wp + k1);
    }
    __syncthreads();

    bf16x8 ah[2], wb[2];
#pragma unroll
    for (int i = 0; i < 2; ++i)
      ah[i] = *(const bf16x8*)&As[wm + i * 16 + col][quad * 8];
#pragma unroll
    for (int j = 0; j < 2; ++j)
      wb[j] = *(const bf16x8*)&Ws[wn + j * 16 + col][quad * 8];
#pragma unroll
    for (int i = 0; i < 2; ++i)
#pragma unroll
      for (int j = 0; j < 2; ++j)
        acc[i][j] = __builtin_amdgcn_mfma_f32_16x16x32_bf16(ah[i], wb[j], acc[i][j], 0, 0, 0);
  }

#pragma unroll
  for (int i = 0; i < 2; ++i)
#pragma unroll
    for (int j = 0; j < 2; ++j)
#pragma unroll
      for (int r = 0; r < 4; ++r) {
        int m = m0 + wm + i * 16 + (quad << 2) + r;
        int n = n0 + wn + j * 16 + col;
        int b = m >> 11, q = m & 2047, h = n >> 6, dd = n & 63;
        Qbf[((size_t)(b * 8 + h) * 2048 + q) * 64 + dd] = f2b(acc[i][j][r]);
      }
}

// ---------------------------------------------------------------------------
// proj_out: out fp32 = attnb (bf16) @ Wo, pipelined LDS staging.
__global__ __launch_bounds__(256) void proj_out_kernel(
    const ushort* __restrict__ A, const ushort* __restrict__ Wt, float* __restrict__ C) {
  __shared__ __align__(16) ushort As[64][PLD];
  __shared__ __align__(16) ushort Ws[64][PLD];

  const int tid = threadIdx.x;
  const int lane = tid & 63;
  const int w = tid >> 6;
  const int col = lane & 15;
  const int quad = lane >> 4;
  const int m0 = blockIdx.y * 64;
  const int n0 = blockIdx.x * 64;
  const int wm = (w & 1) * 32;
  const int wn = (w >> 1) * 32;
  const int ar = tid >> 2;
  const int ak = (tid & 3) * 8;
  const int wn2 = tid >> 2;
  const int wkc = (tid & 3) * 8;

  f32x4 acc[2][2];
#pragma unroll
  for (int i = 0; i < 2; ++i)
#pragma unroll
    for (int j = 0; j < 2; ++j) acc[i][j] = f32x4{0.f, 0.f, 0.f, 0.f};

  const ushort* Ap = A + (size_t)(m0 + ar) * 512 + ak;
  const ushort* Wp = Wt + (size_t)(n0 + wn2) * 512 + wkc;
  bf16x8 apre = *(const bf16x8*)Ap;
  bf16x8 wp = *(const bf16x8*)Wp;

  for (int kt = 0; kt < 16; ++kt) {
    if (kt) __syncthreads();
    *(bf16x8*)&As[ar][ak] = apre;
    *(bf16x8*)&Ws[wn2][wkc] = wp;
    if (kt < 15) {
      const int k1 = (kt + 1) * 32;
      apre = *(const bf16x8*)(Ap + k1);
      wp = *(const bf16x8*)(Wp + k1);
    }
    __syncthreads();

    bf16x8 ah[2], wb[2];
#pragma unroll
    for (int i = 0; i < 2; ++i)
      ah[i] = *(const bf16x8*)&As[wm + i * 16 + col][quad * 8];
#pragma unroll
    for (int j = 0; j < 2; ++j)
      wb[j] = *(const bf16x8*)&Ws[wn + j * 16 + col][quad * 8];
#pragma unroll
    for (int i = 0; i < 2; ++i)
#pragma unroll
      for (int j = 0; j < 2; ++j)
        acc[i][j] = __builtin_amdgcn_mfma_f32_16x16x32_bf16(ah[i], wb[j], acc[i][j], 0, 0, 0);
  }

#pragma unroll
  for (int i = 0; i < 2; ++i)
#pragma unroll
    for (int j = 0; j < 2; ++j)
#pragma unroll
      for (int r = 0; r < 4; ++r)
        C[(size_t)(m0 + wm + i * 16 + (quad << 2) + r) * 512 + n0 + wn + j * 16 + col] =
            acc[i][j][r];
}

// ---------------------------------------------------------------------------
// Flash attention: S^T orientation, static-max softmax, ballot mask,
// PV via LDS P-roundtrip + 16x16x32 MFMA, l accumulated by MFMA(P, ones).
__global__ __launch_bounds__(256) void flash_attn_kernel(
    const ushort* __restrict__ Qbf, const ushort* __restrict__ Kbf,
    const ushort* __restrict__ Vtbf, const uint4* __restrict__ keep4,
    ushort* __restrict__ Op) {
  __shared__ __align__(16) ushort Ks[128][72];
  __shared__ __align__(16) ushort Vt[64][136];
  __shared__ __align__(16) ushort PQ[64][136];  // Q staged first; reused as P[q][k]

  const int bid = blockIdx.x;
  const int qt = bid & 31;
  const int bh = bid >> 5;
  const int b = bh >> 3, h = bh & 7;
  const int q0 = qt * 64;
  const int tid = threadIdx.x, lane = tid & 63, w = tid >> 6;
  const int col = lane & 15, quad = lane >> 4, quad4 = quad * 4;

  // stage Q (64x64 bf16) into PQ[:][0..63], grab B-frags
  const ushort* Qt = Qbf + (size_t)(bh * 2048 + q0) * 64;
#pragma unroll
  for (int i = 0; i < 2; ++i) {
    int c = i * 256 + tid;
    *(bf16x8*)&PQ[c >> 3][(c & 7) * 8] = *(const bf16x8*)(Qt + c * 8);
  }
  __syncthreads();
  const bf16x8 qb0 = *(const bf16x8*)&PQ[w * 16 + col][quad * 8];
  const bf16x8 qb1 = *(const bf16x8*)&PQ[w * 16 + col][32 + quad * 8];
  __syncthreads();  // Q reads done before PQ reused as P storage

  f32x4 oacc[4];
#pragma unroll
  for (int c = 0; c < 4; ++c) oacc[c] = f32x4{0.f, 0.f, 0.f, 0.f};
  f32x4 lacc = f32x4{0.f, 0.f, 0.f, 0.f};

  // ones B-fragment for l row-sums (bf16 1.0 = 0x3F80)
  union { ushort u[8]; bf16x8 v; } onesu;
#pragma unroll
  for (int j = 0; j < 8; ++j) onesu.u[j] = 0x3F80;
  const bf16x8 onesB = onesu.v;

  const uint4* kr = keep4 + (size_t)(b * 2048 + q0 + w * 16 + col) * 16;
  const ushort* Kbase = Kbf + (size_t)bh * 2048 * 64;
  const ushort* Vbase = Vtbf + (size_t)bh * 64 * 2048;

  bf16x8 kpre[4], vpre[4];
  uint4 kw = kr[0];
#pragma unroll
  for (int i = 0; i < 4; ++i) {
    int c = i * 256 + tid;
    kpre[i] = *(const bf16x8*)(Kbase + (size_t)c * 8);
    int d = c >> 4, k8 = (c & 15) * 8;
    vpre[i] = *(const bf16x8*)(Vbase + (size_t)d * 2048 + k8);
  }

  for (int kt = 0; kt < 16; ++kt) {
    if (kt) __syncthreads();
#pragma unroll
    for (int i = 0; i < 4; ++i) {
      int c = i * 256 + tid;
      *(bf16x8*)&Ks[c >> 3][(c & 7) * 8] = kpre[i];
      int d = c >> 4, k8 = (c & 15) * 8;
      *(bf16x8*)&Vt[d][k8] = vpre[i];
    }
    uint4 kwn = kw;
    if (kt < 15) {
      const int k1 = (kt + 1) * 128;
      kwn = kr[kt + 1];
#pragma unroll
      for (int i = 0; i < 4; ++i) {
        int c = i * 256 + tid;
        kpre[i] = *(const bf16x8*)(Kbase + (size_t)k1 * 64 + c * 8);
        int d = c >> 4, k8 = (c & 15) * 8;
        vpre[i] = *(const bf16x8*)(Vbase + (size_t)d * 2048 + k1 + k8);
      }
    }
    __syncthreads();

    // S^T: 128 k-rows x 16 q-cols per wave
    f32x4 sc[8];
#pragma unroll
    for (int t = 0; t < 8; ++t) sc[t] = f32x4{0.f, 0.f, 0.f, 0.f};
#pragma unroll
    for (int t = 0; t < 8; ++t) {
      bf16x8 ka0 = *(const bf16x8*)&Ks[t * 16 + col][quad * 8];
      bf16x8 ka1 = *(const bf16x8*)&Ks[t * 16 + col][32 + quad * 8];
      sc[t] = __builtin_amdgcn_mfma_f32_16x16x32_bf16(ka0, qb0, sc[t], 0, 0, 0);
      sc[t] = __builtin_amdgcn_mfma_f32_16x16x32_bf16(ka1, qb1, sc[t], 0, 0, 0);
    }

    // static-max softmax: p = 2^(s*SL) * keep; pack to P^T in LDS (packed cvt)
    const uint mx_ = kw.x >> quad, my_ = kw.y >> quad, mz_ = kw.z >> quad, mw_ = kw.w >> quad;
#pragma unroll
    for (int t = 0; t < 8; ++t) {
      const int sh = 4 * t;
      float p0 = ((mx_ >> sh) & 1u) ? exp2f(sc[t][0] * SL) : 0.f;
      float p1 = ((my_ >> sh) & 1u) ? exp2f(sc[t][1] * SL) : 0.f;
      float p2 = ((mz_ >> sh) & 1u) ? exp2f(sc[t][2] * SL) : 0.f;
      float p3 = ((mw_ >> sh) & 1u) ? exp2f(sc[t][3] * SL) : 0.f;
      __hip_bfloat162 lo = __float22bfloat162_rn(float2{p0, p1});
      __hip_bfloat162 hi = __float22bfloat162_rn(float2{p2, p3});
      union { __hip_bfloat162 b2[2]; u16x4 v; } pk;
      pk.b2[0] = lo; pk.b2[1] = hi;
      *(u16x4*)&PQ[w * 16 + col][t * 16 + quad4] = pk.v;
    }
    __threadfence_block();

    bf16x8 pa[4];
#pragma unroll
    for (int kb = 0; kb < 4; ++kb)
      pa[kb] = *(const bf16x8*)&PQ[w * 16 + col][kb * 32 + quad * 8];
#pragma unroll
    for (int kb = 0; kb < 4; ++kb) {
      lacc = __builtin_amdgcn_mfma_f32_16x16x32_bf16(pa[kb], onesB, lacc, 0, 0, 0);
#pragma unroll
      for (int c = 0; c < 4; ++c) {
        bf16x8 vb = *(const bf16x8*)&Vt[c * 16 + col][kb * 32 + quad * 8];
        oacc[c] = __builtin_amdgcn_mfma_f32_16x16x32_bf16(pa[kb], vb, oacc[c], 0, 0, 0);
      }
    }
    kw = kwn;
  }

  // lacc[r] = l for q-row w*16+quad4+r (replicated across cols) — no shuffles
  float invO[4];
#pragma unroll
  for (int r = 0; r < 4; ++r) invO[r] = 1.f / lacc[r];
#pragma unroll
  for (int c = 0; c < 4; ++c)
#pragma unroll
    for (int r = 0; r < 4; ++r)
      Op[(size_t)(b * S + q0 + w * 16 + quad4 + r) * HD + h * D + c * 16 + col] =
          f2b(oacc[c][r] * invO[r]);
}

}  // namespace

extern "C" void kernel_launch(void* const* d_in, const int* in_sizes, int n_in,
                              void* d_out, int out_size, void* d_ws, size_t ws_size,
                              hipStream_t stream) {
  const float* inputs = (const float*)d_in[0];   // (B,S,E)
  const float* keys   = (const float*)d_in[1];   // (B,S,H,D)
  const float* values = (const float*)d_in[2];   // (B,S,H,D)
  const float* wq     = (const float*)d_in[3];   // (E, HD)
  const float* wo     = (const float*)d_in[4];   // (HD, E)
  const int*   maskp  = (const int*)d_in[5];     // (B,S,S) bool as int32
  float* out = (float*)d_out;                    // (B,S,E)

  // d_out (8 MB) doubles as scratch for K/V bf16 until proj_out overwrites it.
  ushort* Kbf  = (ushort*)d_out;                 // (B,H,S,D) bf16, 4 MB
  ushort* Vtbf = Kbf + (size_t)2097152;          // (B,H,D,S) bf16, 4 MB

  char* ws = (char*)d_ws;
  ushort* Qbf   = (ushort*)ws;                   // 4 MB
  ushort* attnb = (ushort*)(ws + (4 << 20));     // 4 MB
  uint4*  keep4 = (uint4*)(ws + (8 << 20));      // 1 MB
  ushort* Wtq   = (ushort*)(ws + (9 << 20));     // 0.5 MB
  ushort* Wto   = (ushort*)(ws + (9 << 20) + (512 << 10));  // 0.5 MB

  dim3 blk(256);
  prep_fused_kernel<<<dim3(8832), blk, 0, stream>>>(keys, values, wq, wo, maskp,
                                                    Kbf, Vtbf, Wtq, Wto, keep4);
  proj_q_kernel<<<dim3(8, 64), blk, 0, stream>>>(inputs, Wtq, Qbf);
  flash_attn_kernel<<<dim3(512), blk, 0, stream>>>(Qbf, Kbf, Vtbf, keep4, attnb);
  proj_out_kernel<<<dim3(8, 64), blk, 0, stream>>>(attnb, Wto, out);
}